// Round 6
// baseline (293.790 us; speedup 1.0000x reference)
//
#include <hip/hip_runtime.h>

#define M_DIM 8192
#define N_DIM 4096
#define K_DIM 4096

typedef __bf16 bf16x8 __attribute__((ext_vector_type(8)));
typedef float f32x4 __attribute__((ext_vector_type(4)));

// bf16 round-to-nearest-even from fp32 (no NaN in this problem)
__device__ __forceinline__ unsigned short f2bf(float f) {
    unsigned u = __float_as_uint(f);
    u += 0x7FFFu + ((u >> 16) & 1u);
    return (unsigned short)(u >> 16);
}

// Bit-exact replica of reference _cast_e4m3 (round-half-even, subnormals, sat 448)
__device__ __forceinline__ float cast_e4m3(float v) {
    float a = fminf(fabsf(v), 448.0f);
    float am = fmaxf(a, 0x1p-9f);
    int e = (int)((__float_as_uint(am) >> 23) & 0xFFu) - 127;   // floor(log2(am)), exact
    e = (e < -6) ? -6 : e;
    float step = __uint_as_float((unsigned)(e - 3 + 127) << 23); // 2^(e-3)
    float q = rintf(a / step) * step;                            // a/step exact, RNE tie
    q = fminf(q, 448.0f);
    return (v < 0.0f) ? -q : q;
}

// x: per-row 1x128 blocks. One 32-lane group per block, 4 floats/lane.
__global__ __launch_bounds__(256) void quant_x(const float* __restrict__ X,
                                               unsigned short* __restrict__ Xq) {
    const int g = threadIdx.x >> 5;
    const int l = threadIdx.x & 31;
    const long rb = (long)blockIdx.x * 8 + g;
    const int row = (int)(rb >> 5);
    const int kb = (int)(rb & 31);
    const size_t base = (size_t)row * K_DIM + kb * 128 + l * 4;
    const float4 v = *(const float4*)&X[base];
    float amax = fmaxf(fmaxf(fabsf(v.x), fabsf(v.y)), fmaxf(fabsf(v.z), fabsf(v.w)));
    #pragma unroll
    for (int m = 16; m >= 1; m >>= 1)
        amax = fmaxf(amax, __shfl_xor(amax, m));
    const float scale = fmaxf(amax, 1e-12f) / 448.0f;
    ushort4 o;
    o.x = f2bf(cast_e4m3(v.x / scale) * scale);
    o.y = f2bf(cast_e4m3(v.y / scale) * scale);
    o.z = f2bf(cast_e4m3(v.z / scale) * scale);
    o.w = f2bf(cast_e4m3(v.w / scale) * scale);
    *(ushort4*)&Xq[base] = o;
}

// w: 128x128 tiles. One 256-thread block per tile; values held in registers.
__global__ __launch_bounds__(256) void quant_w(const float* __restrict__ W,
                                               unsigned short* __restrict__ Wq) {
    const int tile = blockIdx.x;
    const int tr = tile >> 5;
    const int tc = tile & 31;
    const int t = threadIdx.x;
    const int c4 = (t & 31) * 4;
    const float* base = W + (size_t)(tr * 128) * K_DIM + tc * 128;

    float4 v[16];
    float amax = 0.0f;
    #pragma unroll
    for (int p = 0; p < 16; ++p) {
        const int r = p * 8 + (t >> 5);
        v[p] = *(const float4*)&base[(size_t)r * K_DIM + c4];
        amax = fmaxf(amax, fmaxf(fmaxf(fabsf(v[p].x), fabsf(v[p].y)),
                                 fmaxf(fabsf(v[p].z), fabsf(v[p].w))));
    }
    #pragma unroll
    for (int m = 32; m >= 1; m >>= 1)
        amax = fmaxf(amax, __shfl_xor(amax, m));
    __shared__ float red[4];
    if ((t & 63) == 0) red[t >> 6] = amax;
    __syncthreads();
    const float am4 = fmaxf(fmaxf(red[0], red[1]), fmaxf(red[2], red[3]));
    const float scale = fmaxf(am4, 1e-12f) / 448.0f;

    unsigned short* out = Wq + (size_t)(tr * 128) * K_DIM + tc * 128;
    #pragma unroll
    for (int p = 0; p < 16; ++p) {
        const int r = p * 8 + (t >> 5);
        ushort4 o;
        o.x = f2bf(cast_e4m3(v[p].x / scale) * scale);
        o.y = f2bf(cast_e4m3(v[p].y / scale) * scale);
        o.z = f2bf(cast_e4m3(v[p].z / scale) * scale);
        o.w = f2bf(cast_e4m3(v[p].w / scale) * scale);
        *(ushort4*)&out[(size_t)r * K_DIM + c4] = o;
    }
}

#define GLOAD16(g, l)                                                          \
    __builtin_amdgcn_global_load_lds(                                          \
        (const __attribute__((address_space(1))) void*)(g),                    \
        (__attribute__((address_space(3))) void*)(l), 16, 0, 0)

// ===================== 256x256 8-phase GEMM, BK=64, 8 waves =====================
// C[M,N] = A[M,K] * B[N,K]^T + bias.  LDS element bases:
//   A buf0: 0      A buf1: 16384   B buf0: 32768   B buf1: 49152   (x2B = 128KiB)
// Even K-tile -> buf0, odd -> buf1.  READ order (per tile): P1 loads A-frags
// (LDA0) AND both B-frag sets (b0,b1) -> B-buf dead after P1; P3 loads LDA(1)
// -> A-buf dead after P3.
// STAGE ledger (iter computes u @P1-4, u+1 @P5-8); one half-tile (2 loads)/phase:
//   P1:A1(u+1)  P2:B0(u+2)  P3:B1(u+2)  P4:A0(u+2)+vmcnt(6)
//   P5:A1(u+2)  P6:B0(u+3)  P7:B1(u+3)  P8:A0(u+3)+vmcnt(6)
// In-flight accounting (steady state): each vmcnt(6) leaves exactly the 3
// newest half-tiles in flight and drains everything the next 4 phases read;
// the oldest drained load was issued 3-4 phases (~900-1200cy) earlier, so the
// wait covers HBM latency (the R5 vmcnt(4) drained 2-3-phase-old loads ->
// boundary stall; R4's failure was P7 reading A1(u+1) left in flight).
// Every stage targets a region whose reads completed >=1 barrier earlier
// (reads complete at that phase's lgkmcnt(0), which precedes its trailing
// barrier). kt is clamped to 63: the tail iterations stage dead data that is
// never read, letting the loop run all 64 tiles with no tapered epilogue.
// Swizzle (3-bit on row bits 0-2, R5-verified conflict-free): LDS[row][c]
// holds element (row, c ^ ((row&7)<<3)); linear LDS dest + inverse-permuted
// global source col; bank-quad coverage proven by SQ_LDS_BANK_CONFLICT == 0.

#define BARRIER() __builtin_amdgcn_s_barrier()
#define LGKM0() asm volatile("s_waitcnt lgkmcnt(0)" ::: "memory")
#define LGKM8() asm volatile("s_waitcnt lgkmcnt(8)" ::: "memory")
#define VM6()   asm volatile("s_waitcnt vmcnt(6)" ::: "memory")
#define VM0()   asm volatile("s_waitcnt vmcnt(0)" ::: "memory")

#define STAGE(G, grow0, kt, ebase, ht) do {                                    \
    const int _kt = (kt) > 63 ? 63 : (kt);                                     \
    const unsigned short* _s0 = (G) +                                          \
        (size_t)((grow0) + (ht) * 128 + w * 8 + sr) * K_DIM + _kt * 64 + src_col; \
    const unsigned short* _s1 = _s0 + (size_t)64 * K_DIM;                      \
    char* _lb = (char*)lds + (ebase) * 2 + ((ht) * 128 + w * 8) * 128;         \
    GLOAD16(_s0, _lb);                                                         \
    GLOAD16(_s1, _lb + 8192);                                                  \
} while (0)

#define LDA(mh, ebase) do {                                                    \
    _Pragma("unroll") for (int _m = 0; _m < 4; ++_m) {                         \
        const int _row = wm * 128 + (mh) * 64 + _m * 16 + lr;                  \
        a[_m][0] = *(const bf16x8*)&lds[(ebase) + _row * 64 + ((0  + hk) ^ rsw)]; \
        a[_m][1] = *(const bf16x8*)&lds[(ebase) + _row * 64 + ((32 + hk) ^ rsw)]; \
    }                                                                          \
} while (0)

#define LDB(nh, dst, ebase) do {                                               \
    _Pragma("unroll") for (int _n = 0; _n < 2; ++_n) {                         \
        const int _row = wn * 64 + (nh) * 32 + _n * 16 + lr;                   \
        dst[_n][0] = *(const bf16x8*)&lds[(ebase) + _row * 64 + ((0  + hk) ^ rsw)]; \
        dst[_n][1] = *(const bf16x8*)&lds[(ebase) + _row * 64 + ((32 + hk) ^ rsw)]; \
    }                                                                          \
} while (0)

#define MMA(mh, nh, bb) do {                                                   \
    _Pragma("unroll") for (int _m = 0; _m < 4; ++_m)                           \
    _Pragma("unroll") for (int _n = 0; _n < 2; ++_n)                           \
    _Pragma("unroll") for (int _k = 0; _k < 2; ++_k)                           \
        acc[(mh) * 4 + _m][(nh) * 2 + _n] =                                    \
            __builtin_amdgcn_mfma_f32_16x16x32_bf16(                           \
                a[_m][_k], bb[_n][_k], acc[(mh) * 4 + _m][(nh) * 2 + _n], 0, 0, 0); \
} while (0)

#define PRIO1() __builtin_amdgcn_s_setprio(1)
#define PRIO0() __builtin_amdgcn_s_setprio(0)

__global__ __launch_bounds__(512, 2) void gemm256(const unsigned short* __restrict__ A,
                                                  const unsigned short* __restrict__ B,
                                                  const float* __restrict__ bias,
                                                  float* __restrict__ C) {
    __shared__ __align__(16) unsigned short lds[65536];   // 128 KiB

    const int t = threadIdx.x;
    const int lane = t & 63;
    const int w = t >> 6;                 // 0..7
    const int wm = w >> 2, wn = w & 3;    // 2M x 4N wave grid

    int bid = blockIdx.x;
    bid = (bid & 7) * 64 + (bid >> 3);    // 512 blocks, %8==0 -> bijective
    const int bm = bid >> 4, bn = bid & 15;
    const size_t brow = (size_t)bm * 256, bcol = (size_t)bn * 256;

    // stage-side lane constants: row-in-8 = lane>>3; inverse-swizzled source col
    const int sr = lane >> 3;
    const int src_col = (((lane & 7) ^ ((lane >> 3) & 7)) << 3);
    // read-side lane constants
    const int lr = lane & 15;
    const int hk = (lane >> 4) * 8;
    const int rsw = (lane & 7) << 3;      // col ^= (row&7)<<3, row&7 == lane&7

    f32x4 acc[8][4] = {};
    bf16x8 a[4][2], b0[2][2], b1[2][2];

    // prologue: tile0 A+B -> buf0, tile1 B + A-half0 -> buf1 (7 half-tiles);
    // vmcnt(6) leaves the 3 newest in flight = steady-state P1 entry.
    STAGE(A, brow, 0, 0, 0);     STAGE(A, brow, 0, 0, 1);
    STAGE(B, bcol, 0, 32768, 0); STAGE(B, bcol, 0, 32768, 1);
    STAGE(B, bcol, 1, 49152, 0); STAGE(B, bcol, 1, 49152, 1);
    STAGE(A, brow, 1, 16384, 0);
    VM6(); BARRIER();

    for (int u = 0; u < 64; u += 2) {
        // P1: reads A0-frags + BOTH B-frag sets of tile u (16 ds_reads)
        LDA(0, 0); LDB(0, b0, 32768); LDB(1, b1, 32768);
        STAGE(A, brow, u + 1, 16384, 1);       // A1(u+1)
        LGKM8();
        BARRIER(); LGKM0();
        PRIO1(); MMA(0, 0, b0); PRIO0();
        BARRIER();
        // P2 (no ds_reads)
        STAGE(B, bcol, u + 2, 32768, 0);       // B0(u+2)
        BARRIER();
        PRIO1(); MMA(0, 1, b1); PRIO0();
        BARRIER();
        // P3
        LDA(1, 0);
        STAGE(B, bcol, u + 2, 32768, 1);       // B1(u+2)
        BARRIER(); LGKM0();
        PRIO1(); MMA(1, 1, b1); PRIO0();
        BARRIER();
        // P4: K-tile boundary
        STAGE(A, brow, u + 2, 0, 0);           // A0(u+2)
        BARRIER();
        PRIO1(); MMA(1, 0, b0); PRIO0();
        VM6();
        BARRIER();
        // P5: tile u+1 (buf1)
        LDA(0, 16384); LDB(0, b0, 49152); LDB(1, b1, 49152);
        STAGE(A, brow, u + 2, 0, 1);           // A1(u+2)
        LGKM8();
        BARRIER(); LGKM0();
        PRIO1(); MMA(0, 0, b0); PRIO0();
        BARRIER();
        // P6
        STAGE(B, bcol, u + 3, 49152, 0);       // B0(u+3)
        BARRIER();
        PRIO1(); MMA(0, 1, b1); PRIO0();
        BARRIER();
        // P7
        LDA(1, 16384);
        STAGE(B, bcol, u + 3, 49152, 1);       // B1(u+3)
        BARRIER(); LGKM0();
        PRIO1(); MMA(1, 1, b1); PRIO0();
        BARRIER();
        // P8: K-tile boundary
        STAGE(A, brow, u + 3, 16384, 0);       // A0(u+3)
        BARRIER();
        PRIO1(); MMA(1, 0, b0); PRIO0();
        VM6();
        BARRIER();
    }

    VM0();   // drain tail stages so no gload_lds is in flight at endpgm

    // C write: acc[i][j] -> row = wm*128 + i*16 + (lane>>4)*4 + jj, col = wn*64 + j*16 + (lane&15)
    #pragma unroll
    for (int i = 0; i < 8; ++i) {
        const size_t row_base = brow + wm * 128 + i * 16 + (lane >> 4) * 4;
        #pragma unroll
        for (int j = 0; j < 4; ++j) {
            const size_t col = bcol + wn * 64 + j * 16 + lr;
            const float bv = bias[col];
            #pragma unroll
            for (int jj = 0; jj < 4; ++jj)
                C[(row_base + jj) * (size_t)N_DIM + col] = acc[i][j][jj] + bv;
        }
    }
}

extern "C" void kernel_launch(void* const* d_in, const int* in_sizes, int n_in,
                              void* d_out, int out_size, void* d_ws, size_t ws_size,
                              hipStream_t stream) {
    const float* x = (const float*)d_in[0];
    const float* w = (const float*)d_in[1];
    const float* bias = (const float*)d_in[2];
    float* out = (float*)d_out;

    unsigned short* xq = (unsigned short*)d_ws;
    unsigned short* wq = xq + (size_t)M_DIM * K_DIM;

    quant_x<<<(M_DIM * (K_DIM / 128)) / 8, 256, 0, stream>>>(x, xq);
    quant_w<<<(N_DIM / 128) * (K_DIM / 128), 256, 0, stream>>>(w, wq);
    gemm256<<<(M_DIM / 256) * (N_DIM / 256), 512, 0, stream>>>(xq, wq, bias, out);
}